// Round 29
// baseline (49742.255 us; speedup 1.0000x reference)
//
#include <hip/hip_runtime.h>
#include <hip/hip_bf16.h>
#include <math.h>

#define N_ROWS 4096
#define M_COLS 8192
#define D_DIM  1024
#define TOPK   32
#define N_ITERS 15
#define CHUNK   2048
#define KC      384
#define D_CUT   1696    // rows with 0 < d <= D_CUT take trajectory B, else A

// ===========================================================================
// topk+pre (R24/R26/R28 bits): register row + cached per-thread argmax.
// A: pairwise-8 norm + idx-sorted KC-folded f32 einsum.
// B: exact f64 dots, f32 store.
// ===========================================================================
template <int EXACT_V>
__global__ __launch_bounds__(256) void topk_pre_kernel(
    const float* __restrict__ R,
    const float* __restrict__ Y,
    float* __restrict__ pre,
    int* __restrict__ inds_ws,
    int row_off, int write_inds)
{
    __shared__ float s_wv[4];
    __shared__ int   s_wi[4];
    __shared__ float topv[TOPK];
    __shared__ int   topi[TOPK];
    __shared__ int   s_win;
    __shared__ float s_w[TOPK];
    __shared__ int   s_si[TOPK];
    __shared__ float s_sw[TOPK];
    __shared__ float s_norm;

    const int tid    = threadIdx.x;
    const int n_loc  = blockIdx.x;
    const int n_glob = row_off + n_loc;
    const float* Rr  = R + (size_t)n_loc * M_COLS;

    float v[32];
    #pragma unroll
    for (int q = 0; q < 8; ++q) {
        float4 w = reinterpret_cast<const float4*>(Rr)[tid + 256 * q];
        v[4 * q + 0] = w.x; v[4 * q + 1] = w.y;
        v[4 * q + 2] = w.z; v[4 * q + 3] = w.w;
    }

    float cv = -INFINITY; int ci = M_COLS;
    #pragma unroll
    for (int q = 0; q < 8; ++q)
        #pragma unroll
        for (int c = 0; c < 4; ++c) {
            const int m = 4 * q + c;
            const int j = 4 * tid + 1024 * q + c;
            if (v[m] > cv || (v[m] == cv && j < ci)) { cv = v[m]; ci = j; }
        }

    for (int s = 0; s < TOPK; ++s) {
        float bv = cv; int bi = ci;
        #pragma unroll
        for (int off = 32; off > 0; off >>= 1) {
            float ov = __shfl_down(bv, off);
            int   oi = __shfl_down(bi, off);
            if (ov > bv || (ov == bv && oi < bi)) { bv = ov; bi = oi; }
        }
        if ((tid & 63) == 0) { s_wv[tid >> 6] = bv; s_wi[tid >> 6] = bi; }
        __syncthreads();
        if (tid == 0) {
            for (int w = 1; w < 4; ++w) {
                if (s_wv[w] > bv || (s_wv[w] == bv && s_wi[w] < bi)) {
                    bv = s_wv[w]; bi = s_wi[w];
                }
            }
            topv[s] = bv; topi[s] = bi; s_win = bi;
        }
        __syncthreads();
        const int win = s_win;
        if (((win >> 2) & 255) == tid) {
            const int mw = ((win >> 10) << 2) | (win & 3);
            #pragma unroll
            for (int m = 0; m < 32; ++m)
                if (m == mw) v[m] = -INFINITY;
            cv = -INFINITY; ci = M_COLS;
            #pragma unroll
            for (int q = 0; q < 8; ++q)
                #pragma unroll
                for (int c = 0; c < 4; ++c) {
                    const int m = 4 * q + c;
                    const int j = 4 * tid + 1024 * q + c;
                    if (v[m] > cv || (v[m] == cv && j < ci)) { cv = v[m]; ci = j; }
                }
        }
    }

    if (EXACT_V) {
        if (tid == 0) {
            double sum = 0.0;
            for (int k = 0; k < TOPK; ++k) sum += fabs((double)topv[k]);
            s_norm = fmaxf((float)sum, 1e-12f);
        }
    } else {
        if (tid == 0) {
            float r[8];
            #pragma unroll
            for (int j = 0; j < 8; ++j) r[j] = fabsf(topv[j]);
            #pragma unroll
            for (int blk = 8; blk < TOPK; blk += 8)
                #pragma unroll
                for (int j = 0; j < 8; ++j)
                    r[j] = __fadd_rn(r[j], fabsf(topv[blk + j]));
            float s01 = __fadd_rn(r[0], r[1]);
            float s23 = __fadd_rn(r[2], r[3]);
            float s45 = __fadd_rn(r[4], r[5]);
            float s67 = __fadd_rn(r[6], r[7]);
            s_norm = fmaxf(__fadd_rn(__fadd_rn(s01, s23), __fadd_rn(s45, s67)), 1e-12f);
        }
    }
    __syncthreads();
    if (tid < TOPK) s_w[tid] = __fdiv_rn(topv[tid], s_norm);
    __syncthreads();

    if (EXACT_V) {
        double acc[4] = {0.0, 0.0, 0.0, 0.0};
        for (int k = 0; k < TOPK; ++k) {
            const double wk = (double)s_w[k];
            const float* yr = Y + (size_t)topi[k] * D_DIM;
            #pragma unroll
            for (int j = 0; j < 4; ++j)
                acc[j] = fma(wk, (double)yr[tid + 256 * j], acc[j]);
        }
        float* pr = pre + (size_t)n_glob * D_DIM;
        #pragma unroll
        for (int j = 0; j < 4; ++j) pr[tid + 256 * j] = (float)acc[j];
    } else {
        if (tid == 0) {
            for (int k = 0; k < TOPK; ++k) { s_si[k] = topi[k]; s_sw[k] = s_w[k]; }
            for (int a = 1; a < TOPK; ++a) {
                int ia = s_si[a]; float wa = s_sw[a];
                int b = a - 1;
                while (b >= 0 && s_si[b] > ia) {
                    s_si[b + 1] = s_si[b]; s_sw[b + 1] = s_sw[b]; --b;
                }
                s_si[b + 1] = ia; s_sw[b + 1] = wa;
            }
        }
        __syncthreads();
        float tot[4]  = {0.f, 0.f, 0.f, 0.f};
        float part[4] = {0.f, 0.f, 0.f, 0.f};
        int curPan = s_si[0] / KC;
        for (int k = 0; k < TOPK; ++k) {
            const int idx = s_si[k];
            const int pan = idx / KC;
            if (pan != curPan) {
                #pragma unroll
                for (int j = 0; j < 4; ++j) {
                    tot[j] = __fadd_rn(tot[j], part[j]);
                    part[j] = 0.f;
                }
                curPan = pan;
            }
            const float wk = s_sw[k];
            const float* yr = Y + (size_t)idx * D_DIM;
            #pragma unroll
            for (int j = 0; j < 4; ++j)
                part[j] = fmaf(wk, yr[tid + 256 * j], part[j]);
        }
        #pragma unroll
        for (int j = 0; j < 4; ++j) tot[j] = __fadd_rn(tot[j], part[j]);
        float* pr = pre + (size_t)n_glob * D_DIM;
        #pragma unroll
        for (int j = 0; j < 4; ++j) pr[tid + 256 * j] = tot[j];
    }

    if (write_inds && tid < TOPK)
        inds_ws[(size_t)n_glob * TOPK + tid] = topi[tid];
}

// ===========================================================================
// A-GEMM (f32): 128x128, BK=16, 8x8/thread, split-column mapping (R28 bits).
// ===========================================================================
#define ABM 128
#define ABN 128
#define ABK 16

__global__ __launch_bounds__(256) void gemmA_kernel(
    const float* __restrict__ A,
    const float* __restrict__ B,
    float* __restrict__ C)
{
    __shared__ __align__(16) float As[ABK][ABM + 4];
    __shared__ __align__(16) float Bs[ABK][ABN + 4];

    const int tid  = threadIdx.x;
    const int tx   = tid & 15;
    const int ty   = tid >> 4;
    const int row0 = blockIdx.y * ABM;
    const int col0 = blockIdx.x * ABN;

    const int lr = tid >> 1;
    const int lc = (tid & 1) * 8;

    float tot[8][8], acc[8][8];
    #pragma unroll
    for (int i = 0; i < 8; ++i)
        #pragma unroll
        for (int j = 0; j < 8; ++j) { tot[i][j] = 0.f; acc[i][j] = 0.f; }

    for (int k0 = 0; k0 < D_DIM; k0 += ABK) {
        float4 va0 = *reinterpret_cast<const float4*>(A + (size_t)(row0 + lr) * D_DIM + k0 + lc);
        float4 va1 = *reinterpret_cast<const float4*>(A + (size_t)(row0 + lr) * D_DIM + k0 + lc + 4);
        As[lc + 0][lr] = va0.x; As[lc + 1][lr] = va0.y;
        As[lc + 2][lr] = va0.z; As[lc + 3][lr] = va0.w;
        As[lc + 4][lr] = va1.x; As[lc + 5][lr] = va1.y;
        As[lc + 6][lr] = va1.z; As[lc + 7][lr] = va1.w;
        float4 vb0 = *reinterpret_cast<const float4*>(B + (size_t)(col0 + lr) * D_DIM + k0 + lc);
        float4 vb1 = *reinterpret_cast<const float4*>(B + (size_t)(col0 + lr) * D_DIM + k0 + lc + 4);
        Bs[lc + 0][lr] = vb0.x; Bs[lc + 1][lr] = vb0.y;
        Bs[lc + 2][lr] = vb0.z; Bs[lc + 3][lr] = vb0.w;
        Bs[lc + 4][lr] = vb1.x; Bs[lc + 5][lr] = vb1.y;
        Bs[lc + 6][lr] = vb1.z; Bs[lc + 7][lr] = vb1.w;
        __syncthreads();

        #pragma unroll
        for (int kk = 0; kk < ABK; ++kk) {
            float a[8], b[8];
            *reinterpret_cast<float4*>(&a[0]) = *reinterpret_cast<float4*>(&As[kk][ty * 8]);
            *reinterpret_cast<float4*>(&a[4]) = *reinterpret_cast<float4*>(&As[kk][ty * 8 + 4]);
            *reinterpret_cast<float4*>(&b[0]) = *reinterpret_cast<float4*>(&Bs[kk][tx * 4]);
            *reinterpret_cast<float4*>(&b[4]) = *reinterpret_cast<float4*>(&Bs[kk][64 + tx * 4]);
            #pragma unroll
            for (int i = 0; i < 8; ++i)
                #pragma unroll
                for (int j = 0; j < 8; ++j)
                    acc[i][j] = fmaf(a[i], b[j], acc[i][j]);
        }
        __syncthreads();

        const int kend = k0 + ABK;
        if (kend == KC || kend == 2 * KC || kend == D_DIM) {
            #pragma unroll
            for (int i = 0; i < 8; ++i)
                #pragma unroll
                for (int j = 0; j < 8; ++j) {
                    tot[i][j] = __fadd_rn(tot[i][j], acc[i][j]);
                    acc[i][j] = 0.f;
                }
        }
    }

    #pragma unroll
    for (int i = 0; i < 8; ++i) {
        float4 v0 = { tot[i][0], tot[i][1], tot[i][2], tot[i][3] };
        float4 v1 = { tot[i][4], tot[i][5], tot[i][6], tot[i][7] };
        float* cr = C + (size_t)(row0 + ty * 8 + i) * M_COLS + col0;
        *reinterpret_cast<float4*>(cr + tx * 4)      = v0;
        *reinterpret_cast<float4*>(cr + 64 + tx * 4) = v1;
    }
}

// ===========================================================================
// B-GEMM (f64 accumulate, f32 I/O): 128x128, BK=16, 8x8/thread.
// A-tile staged as f64 (lossless convert at staging; broadcast reads are
// conflict-free) -> 8 converts/kk instead of 16.  B-tile f32, split-column
// reads (2-way, free).  Per-element chain unchanged; B is order-insensitive
// anyway (R3/R4 == R18 proven).
// ===========================================================================
#define BBM 128
#define BBN 128
#define BBK 16

__global__ __launch_bounds__(256) void gemmB_kernel(
    const float* __restrict__ A,
    const float* __restrict__ B,
    float* __restrict__ C)
{
    __shared__ __align__(16) double As[BBK][BBM + 2];   // 16.6 KB
    __shared__ __align__(16) float  Bs[BBK][BBN + 4];   //  8.4 KB

    const int tid  = threadIdx.x;
    const int tx   = tid & 15;
    const int ty   = tid >> 4;
    const int row0 = blockIdx.y * BBM;
    const int col0 = blockIdx.x * BBN;

    const int lr = tid >> 1;
    const int lc = (tid & 1) * 8;

    double acc[8][8];
    #pragma unroll
    for (int i = 0; i < 8; ++i)
        #pragma unroll
        for (int j = 0; j < 8; ++j) acc[i][j] = 0.0;

    for (int k0 = 0; k0 < D_DIM; k0 += BBK) {
        float4 va0 = *reinterpret_cast<const float4*>(A + (size_t)(row0 + lr) * D_DIM + k0 + lc);
        float4 va1 = *reinterpret_cast<const float4*>(A + (size_t)(row0 + lr) * D_DIM + k0 + lc + 4);
        As[lc + 0][lr] = (double)va0.x; As[lc + 1][lr] = (double)va0.y;
        As[lc + 2][lr] = (double)va0.z; As[lc + 3][lr] = (double)va0.w;
        As[lc + 4][lr] = (double)va1.x; As[lc + 5][lr] = (double)va1.y;
        As[lc + 6][lr] = (double)va1.z; As[lc + 7][lr] = (double)va1.w;
        float4 vb0 = *reinterpret_cast<const float4*>(B + (size_t)(col0 + lr) * D_DIM + k0 + lc);
        float4 vb1 = *reinterpret_cast<const float4*>(B + (size_t)(col0 + lr) * D_DIM + k0 + lc + 4);
        Bs[lc + 0][lr] = vb0.x; Bs[lc + 1][lr] = vb0.y;
        Bs[lc + 2][lr] = vb0.z; Bs[lc + 3][lr] = vb0.w;
        Bs[lc + 4][lr] = vb1.x; Bs[lc + 5][lr] = vb1.y;
        Bs[lc + 6][lr] = vb1.z; Bs[lc + 7][lr] = vb1.w;
        __syncthreads();

        #pragma unroll
        for (int kk = 0; kk < BBK; ++kk) {
            double a[8], b[8];
            *reinterpret_cast<double2*>(&a[0]) = *reinterpret_cast<double2*>(&As[kk][ty * 8]);
            *reinterpret_cast<double2*>(&a[2]) = *reinterpret_cast<double2*>(&As[kk][ty * 8 + 2]);
            *reinterpret_cast<double2*>(&a[4]) = *reinterpret_cast<double2*>(&As[kk][ty * 8 + 4]);
            *reinterpret_cast<double2*>(&a[6]) = *reinterpret_cast<double2*>(&As[kk][ty * 8 + 6]);
            float bf[8];
            *reinterpret_cast<float4*>(&bf[0]) = *reinterpret_cast<float4*>(&Bs[kk][tx * 4]);
            *reinterpret_cast<float4*>(&bf[4]) = *reinterpret_cast<float4*>(&Bs[kk][64 + tx * 4]);
            #pragma unroll
            for (int j = 0; j < 8; ++j) b[j] = (double)bf[j];
            #pragma unroll
            for (int i = 0; i < 8; ++i)
                #pragma unroll
                for (int j = 0; j < 8; ++j)
                    acc[i][j] = fma(a[i], b[j], acc[i][j]);
        }
        __syncthreads();
    }

    #pragma unroll
    for (int i = 0; i < 8; ++i) {
        float4 v0 = { (float)acc[i][0], (float)acc[i][1],
                      (float)acc[i][2], (float)acc[i][3] };
        float4 v1 = { (float)acc[i][4], (float)acc[i][5],
                      (float)acc[i][6], (float)acc[i][7] };
        float* cr = C + (size_t)(row0 + ty * 8 + i) * M_COLS + col0;
        *reinterpret_cast<float4*>(cr + tx * 4)      = v0;
        *reinterpret_cast<float4*>(cr + 64 + tx * 4) = v1;
    }
}

// ===========================================================================
// Choice (d-rule) + emit — unchanged (R20/R21/R24 bits).
// ===========================================================================
__global__ __launch_bounds__(256) void choice_kernel(
    const int* __restrict__ indsA,
    const int* __restrict__ indsB,
    unsigned char* __restrict__ choice)
{
    const int n = blockIdx.x * 256 + threadIdx.x;
    if (n >= N_ROWS) return;
    int d = 0;
    #pragma unroll
    for (int k = 0; k < TOPK; ++k) {
        int diff = indsA[n * TOPK + k] - indsB[n * TOPK + k];
        if (diff < 0) diff = -diff;
        if (diff > d) d = diff;
    }
    choice[n] = (d > 0 && d <= D_CUT) ? 1 : 0;
}

__global__ __launch_bounds__(256) void emit_kernel(
    const float* __restrict__ preA, const float* __restrict__ preB,
    const int* __restrict__ indsA,  const int* __restrict__ indsB,
    const unsigned char* __restrict__ choice,
    float* __restrict__ out_pre, float* __restrict__ out_inds)
{
    const int n   = blockIdx.x;
    const int tid = threadIdx.x;
    const int c   = choice[n];
    const float* ps = (c ? preB : preA) + (size_t)n * D_DIM;
    const int*   is = (c ? indsB : indsA) + (size_t)n * TOPK;
    float* po = out_pre + (size_t)n * D_DIM;
    #pragma unroll
    for (int j = 0; j < 4; ++j) po[tid + 256 * j] = ps[tid + 256 * j];
    if (tid < TOPK)
        out_inds[(size_t)n * TOPK + tid] = (float)is[tid];
}

// ===========================================================================
extern "C" void kernel_launch(void* const* d_in, const int* in_sizes, int n_in,
                              void* d_out, int out_size, void* d_ws, size_t ws_size,
                              hipStream_t stream)
{
    const float* K_in = (const float*)d_in[0];
    const float* Y    = (const float*)d_in[1];

    char* p = (char*)d_ws;
    float* preA   = (float*)p; p += (size_t)N_ROWS * D_DIM * sizeof(float);
    float* preB   = (float*)p; p += (size_t)N_ROWS * D_DIM * sizeof(float);
    float* Kchunk = (float*)p; p += (size_t)CHUNK * M_COLS * sizeof(float);
    int*   indsA  = (int*)p;   p += (size_t)N_ROWS * TOPK * sizeof(int);
    int*   indsB  = (int*)p;   p += (size_t)N_ROWS * TOPK * sizeof(int);
    unsigned char* choice = (unsigned char*)p;

    float* out_pre  = (float*)d_out;
    float* out_inds = out_pre + (size_t)N_ROWS * D_DIM;

    topk_pre_kernel<0><<<N_ROWS, 256, 0, stream>>>(K_in, Y, preA, indsA, 0, 0);
    topk_pre_kernel<1><<<N_ROWS, 256, 0, stream>>>(K_in, Y, preB, indsB, 0, 0);

    for (int it = 0; it < N_ITERS; ++it) {
        const int wo = (it == N_ITERS - 1) ? 1 : 0;
        for (int c = 0; c < N_ROWS / CHUNK; ++c) {
            gemmA_kernel<<<dim3(M_COLS / ABN, CHUNK / ABM), 256, 0, stream>>>(
                preA + (size_t)c * CHUNK * D_DIM, Y, Kchunk);
            topk_pre_kernel<0><<<CHUNK, 256, 0, stream>>>(
                Kchunk, Y, preA, indsA, c * CHUNK, wo);
            gemmB_kernel<<<dim3(M_COLS / BBN, CHUNK / BBM), 256, 0, stream>>>(
                preB + (size_t)c * CHUNK * D_DIM, Y, Kchunk);
            topk_pre_kernel<1><<<CHUNK, 256, 0, stream>>>(
                Kchunk, Y, preB, indsB, c * CHUNK, wo);
        }
    }

    choice_kernel<<<(N_ROWS + 255) / 256, 256, 0, stream>>>(indsA, indsB, choice);
    emit_kernel<<<N_ROWS, 256, 0, stream>>>(preA, preB, indsA, indsB, choice,
                                            out_pre, out_inds);
}

// Round 30
// 47154.559 us; speedup vs baseline: 1.0549x; 1.0549x over previous
//
#include <hip/hip_runtime.h>
#include <hip/hip_bf16.h>
#include <math.h>

#define N_ROWS 4096
#define M_COLS 8192
#define D_DIM  1024
#define TOPK   32
#define N_ITERS 15
#define CHUNK   2048
#define KC      384
#define D_CUT   1696    // rows with 0 < d <= D_CUT take trajectory B, else A

// ===========================================================================
// topk+pre (R24/R26 bits): register row + cached per-thread argmax.
// A: pairwise-8 norm + idx-sorted KC-folded f32 einsum.
// B: exact f64 dots, f32 store.
// ===========================================================================
template <int EXACT_V>
__global__ __launch_bounds__(256) void topk_pre_kernel(
    const float* __restrict__ R,
    const float* __restrict__ Y,
    float* __restrict__ pre,
    int* __restrict__ inds_ws,
    int row_off, int write_inds)
{
    __shared__ float s_wv[4];
    __shared__ int   s_wi[4];
    __shared__ float topv[TOPK];
    __shared__ int   topi[TOPK];
    __shared__ int   s_win;
    __shared__ float s_w[TOPK];
    __shared__ int   s_si[TOPK];
    __shared__ float s_sw[TOPK];
    __shared__ float s_norm;

    const int tid    = threadIdx.x;
    const int n_loc  = blockIdx.x;
    const int n_glob = row_off + n_loc;
    const float* Rr  = R + (size_t)n_loc * M_COLS;

    float v[32];
    #pragma unroll
    for (int q = 0; q < 8; ++q) {
        float4 w = reinterpret_cast<const float4*>(Rr)[tid + 256 * q];
        v[4 * q + 0] = w.x; v[4 * q + 1] = w.y;
        v[4 * q + 2] = w.z; v[4 * q + 3] = w.w;
    }

    float cv = -INFINITY; int ci = M_COLS;
    #pragma unroll
    for (int q = 0; q < 8; ++q)
        #pragma unroll
        for (int c = 0; c < 4; ++c) {
            const int m = 4 * q + c;
            const int j = 4 * tid + 1024 * q + c;
            if (v[m] > cv || (v[m] == cv && j < ci)) { cv = v[m]; ci = j; }
        }

    for (int s = 0; s < TOPK; ++s) {
        float bv = cv; int bi = ci;
        #pragma unroll
        for (int off = 32; off > 0; off >>= 1) {
            float ov = __shfl_down(bv, off);
            int   oi = __shfl_down(bi, off);
            if (ov > bv || (ov == bv && oi < bi)) { bv = ov; bi = oi; }
        }
        if ((tid & 63) == 0) { s_wv[tid >> 6] = bv; s_wi[tid >> 6] = bi; }
        __syncthreads();
        if (tid == 0) {
            for (int w = 1; w < 4; ++w) {
                if (s_wv[w] > bv || (s_wv[w] == bv && s_wi[w] < bi)) {
                    bv = s_wv[w]; bi = s_wi[w];
                }
            }
            topv[s] = bv; topi[s] = bi; s_win = bi;
        }
        __syncthreads();
        const int win = s_win;
        if (((win >> 2) & 255) == tid) {
            const int mw = ((win >> 10) << 2) | (win & 3);
            #pragma unroll
            for (int m = 0; m < 32; ++m)
                if (m == mw) v[m] = -INFINITY;
            cv = -INFINITY; ci = M_COLS;
            #pragma unroll
            for (int q = 0; q < 8; ++q)
                #pragma unroll
                for (int c = 0; c < 4; ++c) {
                    const int m = 4 * q + c;
                    const int j = 4 * tid + 1024 * q + c;
                    if (v[m] > cv || (v[m] == cv && j < ci)) { cv = v[m]; ci = j; }
                }
        }
    }

    if (EXACT_V) {
        if (tid == 0) {
            double sum = 0.0;
            for (int k = 0; k < TOPK; ++k) sum += fabs((double)topv[k]);
            s_norm = fmaxf((float)sum, 1e-12f);
        }
    } else {
        if (tid == 0) {
            float r[8];
            #pragma unroll
            for (int j = 0; j < 8; ++j) r[j] = fabsf(topv[j]);
            #pragma unroll
            for (int blk = 8; blk < TOPK; blk += 8)
                #pragma unroll
                for (int j = 0; j < 8; ++j)
                    r[j] = __fadd_rn(r[j], fabsf(topv[blk + j]));
            float s01 = __fadd_rn(r[0], r[1]);
            float s23 = __fadd_rn(r[2], r[3]);
            float s45 = __fadd_rn(r[4], r[5]);
            float s67 = __fadd_rn(r[6], r[7]);
            s_norm = fmaxf(__fadd_rn(__fadd_rn(s01, s23), __fadd_rn(s45, s67)), 1e-12f);
        }
    }
    __syncthreads();
    if (tid < TOPK) s_w[tid] = __fdiv_rn(topv[tid], s_norm);
    __syncthreads();

    if (EXACT_V) {
        double acc[4] = {0.0, 0.0, 0.0, 0.0};
        for (int k = 0; k < TOPK; ++k) {
            const double wk = (double)s_w[k];
            const float* yr = Y + (size_t)topi[k] * D_DIM;
            #pragma unroll
            for (int j = 0; j < 4; ++j)
                acc[j] = fma(wk, (double)yr[tid + 256 * j], acc[j]);
        }
        float* pr = pre + (size_t)n_glob * D_DIM;
        #pragma unroll
        for (int j = 0; j < 4; ++j) pr[tid + 256 * j] = (float)acc[j];
    } else {
        if (tid == 0) {
            for (int k = 0; k < TOPK; ++k) { s_si[k] = topi[k]; s_sw[k] = s_w[k]; }
            for (int a = 1; a < TOPK; ++a) {
                int ia = s_si[a]; float wa = s_sw[a];
                int b = a - 1;
                while (b >= 0 && s_si[b] > ia) {
                    s_si[b + 1] = s_si[b]; s_sw[b + 1] = s_sw[b]; --b;
                }
                s_si[b + 1] = ia; s_sw[b + 1] = wa;
            }
        }
        __syncthreads();
        float tot[4]  = {0.f, 0.f, 0.f, 0.f};
        float part[4] = {0.f, 0.f, 0.f, 0.f};
        int curPan = s_si[0] / KC;
        for (int k = 0; k < TOPK; ++k) {
            const int idx = s_si[k];
            const int pan = idx / KC;
            if (pan != curPan) {
                #pragma unroll
                for (int j = 0; j < 4; ++j) {
                    tot[j] = __fadd_rn(tot[j], part[j]);
                    part[j] = 0.f;
                }
                curPan = pan;
            }
            const float wk = s_sw[k];
            const float* yr = Y + (size_t)idx * D_DIM;
            #pragma unroll
            for (int j = 0; j < 4; ++j)
                part[j] = fmaf(wk, yr[tid + 256 * j], part[j]);
        }
        #pragma unroll
        for (int j = 0; j < 4; ++j) tot[j] = __fadd_rn(tot[j], part[j]);
        float* pr = pre + (size_t)n_glob * D_DIM;
        #pragma unroll
        for (int j = 0; j < 4; ++j) pr[tid + 256 * j] = tot[j];
    }

    if (write_inds && tid < TOPK)
        inds_ws[(size_t)n_glob * TOPK + tid] = topi[tid];
}

// ===========================================================================
// A-GEMM (f32): 128x128, BK=16, 8x8/thread.  SPLIT-COLUMN mapping: thread
// tx owns cols {tx*4..+3} and {64+tx*4..+3} -> B-fragment LDS reads are
// 2-way-conflict (free).  Per-element chain unchanged (single acc,
// ascending k, folds at 384/768/1024) -> bit-identical.  (R28 bits.)
// ===========================================================================
#define ABM 128
#define ABN 128
#define ABK 16

__global__ __launch_bounds__(256) void gemmA_kernel(
    const float* __restrict__ A,
    const float* __restrict__ B,
    float* __restrict__ C)
{
    __shared__ __align__(16) float As[ABK][ABM + 4];
    __shared__ __align__(16) float Bs[ABK][ABN + 4];

    const int tid  = threadIdx.x;
    const int tx   = tid & 15;
    const int ty   = tid >> 4;
    const int row0 = blockIdx.y * ABM;
    const int col0 = blockIdx.x * ABN;

    const int lr = tid >> 1;
    const int lc = (tid & 1) * 8;

    float tot[8][8], acc[8][8];
    #pragma unroll
    for (int i = 0; i < 8; ++i)
        #pragma unroll
        for (int j = 0; j < 8; ++j) { tot[i][j] = 0.f; acc[i][j] = 0.f; }

    for (int k0 = 0; k0 < D_DIM; k0 += ABK) {
        float4 va0 = *reinterpret_cast<const float4*>(A + (size_t)(row0 + lr) * D_DIM + k0 + lc);
        float4 va1 = *reinterpret_cast<const float4*>(A + (size_t)(row0 + lr) * D_DIM + k0 + lc + 4);
        As[lc + 0][lr] = va0.x; As[lc + 1][lr] = va0.y;
        As[lc + 2][lr] = va0.z; As[lc + 3][lr] = va0.w;
        As[lc + 4][lr] = va1.x; As[lc + 5][lr] = va1.y;
        As[lc + 6][lr] = va1.z; As[lc + 7][lr] = va1.w;
        float4 vb0 = *reinterpret_cast<const float4*>(B + (size_t)(col0 + lr) * D_DIM + k0 + lc);
        float4 vb1 = *reinterpret_cast<const float4*>(B + (size_t)(col0 + lr) * D_DIM + k0 + lc + 4);
        Bs[lc + 0][lr] = vb0.x; Bs[lc + 1][lr] = vb0.y;
        Bs[lc + 2][lr] = vb0.z; Bs[lc + 3][lr] = vb0.w;
        Bs[lc + 4][lr] = vb1.x; Bs[lc + 5][lr] = vb1.y;
        Bs[lc + 6][lr] = vb1.z; Bs[lc + 7][lr] = vb1.w;
        __syncthreads();

        #pragma unroll
        for (int kk = 0; kk < ABK; ++kk) {
            float a[8], b[8];
            *reinterpret_cast<float4*>(&a[0]) = *reinterpret_cast<float4*>(&As[kk][ty * 8]);
            *reinterpret_cast<float4*>(&a[4]) = *reinterpret_cast<float4*>(&As[kk][ty * 8 + 4]);
            *reinterpret_cast<float4*>(&b[0]) = *reinterpret_cast<float4*>(&Bs[kk][tx * 4]);
            *reinterpret_cast<float4*>(&b[4]) = *reinterpret_cast<float4*>(&Bs[kk][64 + tx * 4]);
            #pragma unroll
            for (int i = 0; i < 8; ++i)
                #pragma unroll
                for (int j = 0; j < 8; ++j)
                    acc[i][j] = fmaf(a[i], b[j], acc[i][j]);
        }
        __syncthreads();

        const int kend = k0 + ABK;
        if (kend == KC || kend == 2 * KC || kend == D_DIM) {
            #pragma unroll
            for (int i = 0; i < 8; ++i)
                #pragma unroll
                for (int j = 0; j < 8; ++j) {
                    tot[i][j] = __fadd_rn(tot[i][j], acc[i][j]);
                    acc[i][j] = 0.f;
                }
        }
    }

    #pragma unroll
    for (int i = 0; i < 8; ++i) {
        float4 v0 = { tot[i][0], tot[i][1], tot[i][2], tot[i][3] };
        float4 v1 = { tot[i][4], tot[i][5], tot[i][6], tot[i][7] };
        float* cr = C + (size_t)(row0 + ty * 8 + i) * M_COLS + col0;
        *reinterpret_cast<float4*>(cr + tx * 4)      = v0;
        *reinterpret_cast<float4*>(cr + 64 + tx * 4) = v1;
    }
}

// ===========================================================================
// B-GEMM (f64 accumulate, f32 I/O): 128x128, BK=32, 8x8/thread, split-column
// mapping (R28 bits).  Chain per element unchanged; B is order-insensitive
// anyway (R3/R4 == R18 proven).
// ===========================================================================
#define BBM 128
#define BBN 128
#define BBK 32

__global__ __launch_bounds__(256) void gemmB_kernel(
    const float* __restrict__ A,
    const float* __restrict__ B,
    float* __restrict__ C)
{
    __shared__ __align__(16) float As[BBK][BBM + 4];
    __shared__ __align__(16) float Bs[BBK][BBN + 4];

    const int tid  = threadIdx.x;
    const int tx   = tid & 15;
    const int ty   = tid >> 4;
    const int row0 = blockIdx.y * BBM;
    const int col0 = blockIdx.x * BBN;

    const int lr = tid >> 1;              // 0..127
    const int lc = (tid & 1) * 16;        // 0 or 16

    double acc[8][8];
    #pragma unroll
    for (int i = 0; i < 8; ++i)
        #pragma unroll
        for (int j = 0; j < 8; ++j) acc[i][j] = 0.0;

    for (int k0 = 0; k0 < D_DIM; k0 += BBK) {
        #pragma unroll
        for (int u = 0; u < 4; ++u) {
            float4 va = *reinterpret_cast<const float4*>(
                A + (size_t)(row0 + lr) * D_DIM + k0 + lc + 4 * u);
            As[lc + 4 * u + 0][lr] = va.x; As[lc + 4 * u + 1][lr] = va.y;
            As[lc + 4 * u + 2][lr] = va.z; As[lc + 4 * u + 3][lr] = va.w;
            float4 vb = *reinterpret_cast<const float4*>(
                B + (size_t)(col0 + lr) * D_DIM + k0 + lc + 4 * u);
            Bs[lc + 4 * u + 0][lr] = vb.x; Bs[lc + 4 * u + 1][lr] = vb.y;
            Bs[lc + 4 * u + 2][lr] = vb.z; Bs[lc + 4 * u + 3][lr] = vb.w;
        }
        __syncthreads();

        #pragma unroll
        for (int kk = 0; kk < BBK; ++kk) {
            float af[8], bf[8];
            *reinterpret_cast<float4*>(&af[0]) = *reinterpret_cast<float4*>(&As[kk][ty * 8]);
            *reinterpret_cast<float4*>(&af[4]) = *reinterpret_cast<float4*>(&As[kk][ty * 8 + 4]);
            *reinterpret_cast<float4*>(&bf[0]) = *reinterpret_cast<float4*>(&Bs[kk][tx * 4]);
            *reinterpret_cast<float4*>(&bf[4]) = *reinterpret_cast<float4*>(&Bs[kk][64 + tx * 4]);
            double a[8], b[8];
            #pragma unroll
            for (int i = 0; i < 8; ++i) a[i] = (double)af[i];
            #pragma unroll
            for (int j = 0; j < 8; ++j) b[j] = (double)bf[j];
            #pragma unroll
            for (int i = 0; i < 8; ++i)
                #pragma unroll
                for (int j = 0; j < 8; ++j)
                    acc[i][j] = fma(a[i], b[j], acc[i][j]);
        }
        __syncthreads();
    }

    #pragma unroll
    for (int i = 0; i < 8; ++i) {
        float4 v0 = { (float)acc[i][0], (float)acc[i][1],
                      (float)acc[i][2], (float)acc[i][3] };
        float4 v1 = { (float)acc[i][4], (float)acc[i][5],
                      (float)acc[i][6], (float)acc[i][7] };
        float* cr = C + (size_t)(row0 + ty * 8 + i) * M_COLS + col0;
        *reinterpret_cast<float4*>(cr + tx * 4)      = v0;
        *reinterpret_cast<float4*>(cr + 64 + tx * 4) = v1;
    }
}

// ===========================================================================
// Choice (d-rule) + emit — unchanged (R20/R21/R24 bits).
// ===========================================================================
__global__ __launch_bounds__(256) void choice_kernel(
    const int* __restrict__ indsA,
    const int* __restrict__ indsB,
    unsigned char* __restrict__ choice)
{
    const int n = blockIdx.x * 256 + threadIdx.x;
    if (n >= N_ROWS) return;
    int d = 0;
    #pragma unroll
    for (int k = 0; k < TOPK; ++k) {
        int diff = indsA[n * TOPK + k] - indsB[n * TOPK + k];
        if (diff < 0) diff = -diff;
        if (diff > d) d = diff;
    }
    choice[n] = (d > 0 && d <= D_CUT) ? 1 : 0;
}

__global__ __launch_bounds__(256) void emit_kernel(
    const float* __restrict__ preA, const float* __restrict__ preB,
    const int* __restrict__ indsA,  const int* __restrict__ indsB,
    const unsigned char* __restrict__ choice,
    float* __restrict__ out_pre, float* __restrict__ out_inds)
{
    const int n   = blockIdx.x;
    const int tid = threadIdx.x;
    const int c   = choice[n];
    const float* ps = (c ? preB : preA) + (size_t)n * D_DIM;
    const int*   is = (c ? indsB : indsA) + (size_t)n * TOPK;
    float* po = out_pre + (size_t)n * D_DIM;
    #pragma unroll
    for (int j = 0; j < 4; ++j) po[tid + 256 * j] = ps[tid + 256 * j];
    if (tid < TOPK)
        out_inds[(size_t)n * TOPK + tid] = (float)is[tid];
}

// ===========================================================================
extern "C" void kernel_launch(void* const* d_in, const int* in_sizes, int n_in,
                              void* d_out, int out_size, void* d_ws, size_t ws_size,
                              hipStream_t stream)
{
    const float* K_in = (const float*)d_in[0];
    const float* Y    = (const float*)d_in[1];

    char* p = (char*)d_ws;
    float* preA   = (float*)p; p += (size_t)N_ROWS * D_DIM * sizeof(float);
    float* preB   = (float*)p; p += (size_t)N_ROWS * D_DIM * sizeof(float);
    float* Kchunk = (float*)p; p += (size_t)CHUNK * M_COLS * sizeof(float);
    int*   indsA  = (int*)p;   p += (size_t)N_ROWS * TOPK * sizeof(int);
    int*   indsB  = (int*)p;   p += (size_t)N_ROWS * TOPK * sizeof(int);
    unsigned char* choice = (unsigned char*)p;

    float* out_pre  = (float*)d_out;
    float* out_inds = out_pre + (size_t)N_ROWS * D_DIM;

    topk_pre_kernel<0><<<N_ROWS, 256, 0, stream>>>(K_in, Y, preA, indsA, 0, 0);
    topk_pre_kernel<1><<<N_ROWS, 256, 0, stream>>>(K_in, Y, preB, indsB, 0, 0);

    for (int it = 0; it < N_ITERS; ++it) {
        const int wo = (it == N_ITERS - 1) ? 1 : 0;
        for (int c = 0; c < N_ROWS / CHUNK; ++c) {
            gemmA_kernel<<<dim3(M_COLS / ABN, CHUNK / ABM), 256, 0, stream>>>(
                preA + (size_t)c * CHUNK * D_DIM, Y, Kchunk);
            topk_pre_kernel<0><<<CHUNK, 256, 0, stream>>>(
                Kchunk, Y, preA, indsA, c * CHUNK, wo);
            gemmB_kernel<<<dim3(M_COLS / BBN, CHUNK / BBM), 256, 0, stream>>>(
                preB + (size_t)c * CHUNK * D_DIM, Y, Kchunk);
            topk_pre_kernel<1><<<CHUNK, 256, 0, stream>>>(
                Kchunk, Y, preB, indsB, c * CHUNK, wo);
        }
    }

    choice_kernel<<<(N_ROWS + 255) / 256, 256, 0, stream>>>(indsA, indsB, choice);
    emit_kernel<<<N_ROWS, 256, 0, stream>>>(preA, preB, indsA, indsB, choice,
                                            out_pre, out_inds);
}